// Round 9
// baseline (414.847 us; speedup 1.0000x reference)
//
#include <hip/hip_runtime.h>

typedef float f32x2 __attribute__((ext_vector_type(2)));

#define IMG_W 512
#define IMG_H 512
#define TY 8
#define PLANES 96              // N*C = 32*3
#define NPIX (32ll * 3 * 512 * 512)
#define NACC 64                // atomic fanout slots
#define NBLOCKS (64 * PLANES)  // 6144

// Separable Gaussian, sigma=1.5, size=11, normalized (compile-time folded).
#define WG_INIT { 0.00102838f, 0.00759876f, 0.03600077f, 0.10936069f, \
                  0.21300553f, 0.26601172f, 0.21300553f, 0.10936069f, \
                  0.03600077f, 0.00759876f, 0.00102838f }

// 4 maps {p, t, p^2+t^2, p*t} (sigma1+sigma2 fused via conv linearity).
// R11: SINGLE-PHASE horizontal in STATIC LDS = exactly 64 KB. All 16 slabs
// (4 maps x 4 row-pairs) live at once: R5's 2-phase profile showed
// VALU% + DS% ~= 100% (barrier-locked convoys; pipes never overlap), and
// R6/R8 proved inst-count shaving doesn't pay. Fit trick: NO zero-pads --
// 16 x 256 atoms x 16 B = 65536; boundary zeros via 6 precomputed masks +
// cndmask on the 24 edge loads. wsum/islast ALIAS into ldsraw after the
// read phase (barrier separates lifetimes).
// KEY: at 64 KB the CU caps at 2 blocks = 16 waves = 4 waves/SIMD no matter
// what VGPR is -> the 64-VGPR cliff (R6 disaster) is moot; 16 waves/CU
// equals R5's MEASURED residency. Hard constraints kept: static LDS only
// (R9 dynamic-LDS scratch disaster), no asm pk-fma (R8).
//
// DS model (validated R5/R6): wave b128 read = 4 inherent "conflict" cyc
// (half rate), stride-1 b64 writes free. pmap bank-group(at) =
// ((at>>1)&7)^((at&1)<<2): conflict-free for stride-2 cross-lane b128 reads
// (8 lanes/cyc -> (at>>1) covers all 8 groups) and stride-1 b64 writes
// (16 lanes/cyc -> 8 atoms, 4-consecutive-mod-8 hits each XOR4 pair once).
// Expect SQ_LDS_BANK_CONFLICT == 6291456 exactly (inherent only).
#define SLAB_ATOMS 256
#define SLAB_BYTES (SLAB_ATOMS * 16)      // 4096
#define NSLABS 16
#define LDS_TOTAL (NSLABS * SLAB_BYTES)   // 65536 = static max

__device__ __forceinline__ int pmap(int at) {
    const int par = at & 1;
    return (at & ~15) | (par << 3) | (((at >> 1) & 7) ^ (par << 2));
}

__global__ __launch_bounds__(512)
void ssim_main(const float* __restrict__ pred, const float* __restrict__ targ,
               double* __restrict__ acc, float* __restrict__ out) {
    const float WG[11] = WG_INIT;

    __shared__ __align__(16) unsigned char ldsraw[LDS_TOTAL];

    const int tid   = threadIdx.x;
    const int x     = tid;                 // column owned in vertical pass
    const int plane = blockIdx.y;
    const int y0    = blockIdx.x * TY;
    const size_t base = (size_t)plane * (IMG_W * IMG_H);
    const float* pCol = pred + base + x;
    const float* tCol = targ + base + x;

    // ---- vertical pass: 18 rows -> 8 output rows as 4 packed row-pairs ----
    float pv[TY + 10], tv[TY + 10];
#pragma unroll
    for (int iy = 0; iy < TY + 10; ++iy) {
        const int y = y0 - 5 + iy;
        pv[iy] = 0.f; tv[iy] = 0.f;
        if ((unsigned)y < (unsigned)IMG_H) {    // wave-uniform
            pv[iy] = pCol[(size_t)y * IMG_W];
            tv[iy] = tCol[(size_t)y * IMG_W];
        }
    }

    f32x2 A[4][4];
#pragma unroll
    for (int m = 0; m < 4; ++m)
#pragma unroll
        for (int rp = 0; rp < 4; ++rp) A[m][rp] = (f32x2){0.f, 0.f};

#pragma unroll
    for (int iy = 0; iy < TY + 10; ++iy) {
        const float p = pv[iy], t = tv[iy];
        const float ss = __builtin_fmaf(t, t, p * p);   // p^2 + t^2
        const float pt = p * t;
        const f32x2 vs[4] = { {p,p}, {t,t}, {ss,ss}, {pt,pt} };
#pragma unroll
        for (int rp = 0; rp < 4; ++rp) {
            const int a = iy - 2 * rp;                      // compile-time
            if (a < 0 || a > 11) continue;                  // both lanes zero
            const float w0 = (a <= 10) ? WG[a] : 0.f;       // row 2rp
            const float w1 = (a >= 1)  ? WG[a - 1] : 0.f;   // row 2rp+1
            const f32x2 w = (f32x2){w0, w1};
#pragma unroll
            for (int m = 0; m < 4; ++m)
                A[m][rp] = __builtin_elementwise_fma(vs[m], w, A[m][rp]);
        }
    }

    // ---- write ALL 16 slabs (no pads: entry == data col), ONE barrier ----
    // thread x -> atom x>>1, b64 half (x&1); stride-1 b64 writes: conflict-free
    const int wof = pmap(x >> 1) * 16 + (x & 1) * 8;
#pragma unroll
    for (int m = 0; m < 4; ++m)
#pragma unroll
        for (int rp = 0; rp < 4; ++rp)
            *(f32x2*)(ldsraw + (m * 4 + rp) * SLAB_BYTES + wof) = A[m][rp];
    __syncthreads();

    // ---- horizontal pass: thread (rpl, g) -> out cols 4g..4g+3, pair rpl ----
    // window: data cols 4g-6..4g+9 = atoms 2g-3..2g+4 (8 atoms, stride-2
    // cross-lane). win[i] = col 4g-6+i; out col 4g+c, tap k -> win[c+1+k].
    // Edge atoms (at<0 or at>255) -> clamp address, zero value via mask.
    const int g   = tid & 127;
    const int rpl = tid >> 7;
    int rof[8]; bool msk[8];
#pragma unroll
    for (int q = 0; q < 8; ++q) {
        const int at  = 2 * g - 3 + q;
        msk[q] = ((unsigned)at <= 255u);          // q=3,4 always true (folds)
        const int atc = min(max(at, 0), 255);
        rof[q] = rpl * SLAB_BYTES + pmap(atc) * 16;
    }

    f32x2 H[4][4];   // [map][col]
#pragma unroll
    for (int ml = 0; ml < 4; ++ml) {
        const unsigned char* slab = ldsraw + ml * (4 * SLAB_BYTES);
        f32x2 win[16];
#pragma unroll
        for (int q = 0; q < 8; ++q) {
            float4 v = *(const float4*)(slab + rof[q]);
            if (!msk[q]) v = (float4){0.f, 0.f, 0.f, 0.f};   // cndmask x4
            win[2 * q]     = (f32x2){v.x, v.y};
            win[2 * q + 1] = (f32x2){v.z, v.w};
        }
        f32x2 hacc[4];
#pragma unroll
        for (int c = 0; c < 4; ++c) hacc[c] = (f32x2){0.f, 0.f};
#pragma unroll
        for (int k = 0; k < 11; ++k) {
            const f32x2 wk = (f32x2){WG[k], WG[k]};
#pragma unroll
            for (int c = 0; c < 4; ++c)
                hacc[c] = __builtin_elementwise_fma(win[c + 1 + k], wk, hacc[c]);
        }
#pragma unroll
        for (int c = 0; c < 4; ++c) H[ml][c] = hacc[c];
    }

    // ---- SSIM on 4 cols x 2 rows ----
    const float C1 = 1e-4f, C2 = 9e-4f;
    float lsum = 0.f;
#pragma unroll
    for (int c = 0; c < 4; ++c) {
        const f32x2 mu1 = H[0][c], mu2 = H[1][c];
        const f32x2 S   = H[2][c], P  = H[3][c];
        const f32x2 mu12 = mu1 * mu2;
        const f32x2 musq = mu1 * mu1 + mu2 * mu2;
        const f32x2 num = (mu12 + mu12 + (f32x2){C1, C1}) *
                          ((P - mu12) + (P - mu12) + (f32x2){C2, C2});
        const f32x2 den = (musq + (f32x2){C1, C1}) *
                          (S - musq + (f32x2){C2, C2}) + (f32x2){1e-8f, 1e-8f};
        lsum += num.x * __builtin_amdgcn_rcpf(den.x);
        lsum += num.y * __builtin_amdgcn_rcpf(den.y);
    }

    // ---- reduction; wsum/islast ALIAS into ldsraw (reads are done) ----
    __syncthreads();                       // all LDS reads complete
    float*  wsum    = (float*)ldsraw;      // [8]
    int*    islastp = (int*)(ldsraw + 64);
#pragma unroll
    for (int off = 32; off > 0; off >>= 1)
        lsum += __shfl_down(lsum, off);
    if ((tid & 63) == 0) wsum[tid >> 6] = lsum;
    __syncthreads();
    unsigned int* cnt = (unsigned int*)(acc + NACC);
    if (tid == 0) {
        float s = 0.f;
#pragma unroll
        for (int i = 0; i < 8; ++i) s += wsum[i];
        atomicAdd(&acc[blockIdx.x & (NACC - 1)], (double)s);
        __threadfence();                   // acc add visible before cnt
        const unsigned int old = atomicAdd(cnt, 1u);
        *islastp = (old == NBLOCKS - 1);
    }
    __syncthreads();

    // ---- fused finalization by the last block (proven R10) ----
    if (*islastp && tid < 64) {
        __threadfence();
        double v = atomicAdd(&acc[tid], 0.0);   // device-coherent read
#pragma unroll
        for (int off = 32; off > 0; off >>= 1)
            v += __shfl_down(v, off);
        if (tid == 0)
            out[0] = 1.0f - (float)(v * (1.0 / (double)NPIX));
    }
}

extern "C" void kernel_launch(void* const* d_in, const int* in_sizes, int n_in,
                              void* d_out, int out_size, void* d_ws, size_t ws_size,
                              hipStream_t stream) {
    const float* pred = (const float*)d_in[0];
    const float* targ = (const float*)d_in[1];
    double* acc = (double*)d_ws;

    // zero acc slots + last-block counter
    hipMemsetAsync(acc, 0, (NACC + 1) * sizeof(double), stream);

    dim3 grid(IMG_H / TY, PLANES);   // 64 x 96 = 6144 blocks
    ssim_main<<<grid, 512, 0, stream>>>(pred, targ, acc, (float*)d_out);
}